// Round 11
// baseline (175.116 us; speedup 1.0000x reference)
//
#include <hip/hip_runtime.h>
#include <hip/hip_bf16.h>
#include <math.h>

#define TT     4096        // T
#define NWG    768         // persistent workgroups (3/CU)
#define PREC   516         // per-batch accumulator: 4*128 P + 4 z
#define NB     64          // batch
#define GTOK   4160        // padded token slots per batch (65*64)

typedef short s16x8 __attribute__((ext_vector_type(8)));
typedef float f32x4 __attribute__((ext_vector_type(4)));

// 100^(-i/7), i=0..7  (inverse timescales)
__device__ __constant__ float INV_TS[8] = {
    1.0f,                 0.5179474679231213f, 0.2682695795279726f, 0.1389495494373138f,
    0.0719685673001152f,  0.0372759372031494f, 0.0193069772888325f, 0.01f };

__device__ __forceinline__ ushort f2bf(float f) {        // RNE (prep only)
    uint u = __float_as_uint(f);
    return (ushort)((u + 0x7fffu + ((u >> 16) & 1u)) >> 16);
}
__device__ __forceinline__ float bf2f(ushort h) {
    return __uint_as_float(((uint)h) << 16);
}
// packed f32x2 -> bf16x2 (RNE), single HW instr on gfx950
__device__ __forceinline__ uint pkbf(float a, float b) {
    union { __hip_bfloat162 h; uint u; } cv;
    cv.h = __float22bfloat162_rn(make_float2(a, b));
    return cv.u;
}
// 16B-granule swizzle: conflict-neutral, but the verified no-spill allocation
// (r7/r9/r10) was achieved WITH it — do not remove (r8 lesson).
__device__ __forceinline__ int hswz(int m, int col) {
    return ((((col >> 3) - 2 * (m & 7)) & 15) << 3) | (col & 7);
}
// pin a fragment into the AGPR file (MFMA sources A/B from AGPR on gfx950)
#define PIN_A(v) asm volatile("" : "+a"(v))

// ---------------- prep: demo enc + zero partials | w_eff | weight prep ----------
__global__ __launch_bounds__(128) void prep_all(
    const float* __restrict__ demo,
    const float* __restrict__ dw1, const float* __restrict__ db1,
    const float* __restrict__ dw2, const float* __restrict__ db2,
    const float* __restrict__ W_k, const float* __restrict__ W_q,
    const float* __restrict__ w1, const float* __restrict__ w2,
    const float* __restrict__ w3,
    float* __restrict__ demo_enc, float* __restrict__ w_eff,
    ushort* __restrict__ ws16, float* __restrict__ partials)
{
    const int b = blockIdx.x, tid = threadIdx.x;
    if (b < NB) {
        for (int j = tid; j < PREC; j += 128) partials[b*PREC + j] = 0.f;
        __shared__ float h[128];
        float a = db1[tid];
#pragma unroll
        for (int k = 0; k < 8; k++) a += demo[b*8 + k] * dw1[k*128 + tid];
        h[tid] = fmaxf(a, 0.f);
        __syncthreads();
        if (tid < 32) {
            float e = db2[tid];
#pragma unroll 8
            for (int k = 0; k < 128; k++) e += h[k] * dw2[k*32 + tid];
            demo_enc[b*32 + tid] = e;
        }
    } else if (b == NB) {
        // w_eff[f][h] = (W_k[f, h*64:(h+1)*64] . W_q[h]) / 8
        const int f = tid >> 2, hh = tid & 3;
        float s = 0.f;
#pragma unroll 8
        for (int d = 0; d < 64; d++) s += W_k[f*256 + hh*64 + d] * W_q[hh*64 + d];
        w_eff[f*4 + hh] = s * 0.125f;
    } else {
        ushort* w1T = ws16;             // [128][32]
        ushort* w2T = ws16 + 4096;      // [128][128]
        ushort* w3T = ws16 + 20480;     // [128][128]
        const int n = (b - 65) & 127, which = (b - 65) >> 7, k = tid;
        if (which == 0)      w2T[n*128 + k] = f2bf(w2[k*128 + n]);
        else if (which == 1) w3T[n*128 + k] = f2bf(w3[k*128 + n]);
        else if (k < 32)     w1T[n*32  + k] = f2bf(w1[k*128 + n]);
    }
}

// ---------------- featurize: all tokens -> bf16 X + fp32 attn logits ------------
__global__ __launch_bounds__(256) void featurize(
    const float* __restrict__ times,  const float* __restrict__ values,
    const int*   __restrict__ meas,
    const float* __restrict__ demo_enc, const float* __restrict__ w_eff,
    ushort* __restrict__ Xbf,          // [NB][GTOK][32]
    float*  __restrict__ slog)         // [NB][GTOK][4]
{
    __shared__ float spart[4][4][64];
    const int b = blockIdx.y, tile = blockIdx.x;        // grid (65, 64)
    const int tid = threadIdx.x, t = tid & 63, g = tid >> 6;
    const int gt = tile*64 + t;

    float x[8];
    if (gt == 0) {
#pragma unroll
        for (int j = 0; j < 8; j++) x[j] = demo_enc[b*32 + g*8 + j];
    } else if (gt <= TT) {
        const int ti = b*TT + gt - 1;
        if (g == 0) {
            float tm = times[ti];
#pragma unroll
            for (int j = 0; j < 8; j++) x[j] = __sinf(tm * INV_TS[j]);
        } else if (g == 1) {
            float tm = times[ti];
#pragma unroll
            for (int j = 0; j < 8; j++) x[j] = __cosf(tm * INV_TS[j]);
        } else if (g == 2) {
            int mm = meas[ti]; x[0] = values[ti];
#pragma unroll
            for (int j = 1; j < 8; j++) x[j] = (mm == j-1) ? 1.f : 0.f;
        } else {
            int mm = meas[ti];
#pragma unroll
            for (int j = 0; j < 8; j++) x[j] = (mm == 7+j) ? 1.f : 0.f;
        }
    } else {
#pragma unroll
        for (int j = 0; j < 8; j++) x[j] = 0.f;
    }
    // logit partials
    {
        float s0 = 0, s1 = 0, s2 = 0, s3 = 0;
#pragma unroll
        for (int j = 0; j < 8; j++) {
            const float* we = w_eff + (g*8 + j)*4;
            s0 += x[j]*we[0]; s1 += x[j]*we[1]; s2 += x[j]*we[2]; s3 += x[j]*we[3];
        }
        spart[g][0][t] = s0; spart[g][1][t] = s1;
        spart[g][2][t] = s2; spart[g][3][t] = s3;
    }
    // pack + store X (bf16)
    {
        uint4 uh = {pkbf(x[0],x[1]), pkbf(x[2],x[3]), pkbf(x[4],x[5]), pkbf(x[6],x[7])};
        *(uint4*)&Xbf[((size_t)b*GTOK + gt)*32 + g*8] = uh;
    }
    __syncthreads();
    // reduced logits: thread (t, head=g)
    {
        float ss = spart[0][g][t] + spart[1][g][t] + spart[2][g][t] + spart[3][g][t];
        slog[((size_t)b*GTOK + gt)*4 + g] = ss;
    }
}

// ---------------- persistent fused main ----------------------------------------
__global__ void __launch_bounds__(256)
__attribute__((amdgpu_waves_per_eu(3, 3)))
fused_main(
    const int*    __restrict__ lengths,
    const ushort* __restrict__ Xbf,   const float* __restrict__ slog,
    const ushort* __restrict__ wT16,
    const float* __restrict__ b1, const float* __restrict__ b2,
    const float* __restrict__ b3,
    float* __restrict__ partials)
{
    const ushort* w1T = wT16;
    const ushort* w2T = wT16 + 4096;
    const ushort* w3T = wT16 + 20480;

    // ---- LDS arena with lifetime-based aliasing (42.75 KB -> 3 WG/CU) ----
    __shared__ __align__(16) char arena[43776];
    ushort (*Hhi )[136]    = (ushort(*)[136])(arena);            // 17408 B
    ushort (*encT)[88]     = (ushort(*)[88]) (arena);            // 22528 B (alias)
    ushort (*H2  )[136]    = (ushort(*)[136])(arena + 22528);    // 17408 B
    ushort (*wexpT)[88]    = (ushort(*)[88]) (arena + 40960);    //  2816 B

    const int tid  = threadIdx.x;
    const int lane = tid & 63, wav = tid >> 6;
    const int l15  = lane & 15, q = lane >> 4;
    const int nb0  = wav * 32;
    const int t    = lane;                  // token slot

    // zero wexpT rows 4..15 once (A-operand padding rows)
    for (int i = tid; i < 12*88/2; i += 256) ((uint*)&wexpT[4][0])[i] = 0u;

    // ---- load weight fragments ONCE; they live in AGPRs across the whole loop --
    s16x8 ah1[2];    f32x4 bv1[2];
    s16x8 ah2[2][4]; f32x4 bv2[2];
    s16x8 wb3[2][4]; float b3l[2];
#pragma unroll
    for (int nt = 0; nt < 2; nt++) {
        const int np = nb0 + nt*16 + l15;
        ah1[nt] = *(const s16x8*)(w1T + np*32 + q*8);
        bv1[nt] = *(const f32x4*)(b1 + nb0 + nt*16 + q*4);
#pragma unroll
        for (int ks = 0; ks < 4; ks++) {
            ah2[nt][ks] = *(const s16x8*)(w2T + np*128 + ks*32 + q*8);
            wb3[nt][ks] = *(const s16x8*)(w3T + np*128 + ks*32 + q*8);
        }
        bv2[nt] = *(const f32x4*)(b2 + nb0 + nt*16 + q*4);
        b3l[nt] = b3[np];
    }

    // ---- contiguous chunk range for this WG (b-locality -> register P-accum) ----
    const int wg = blockIdx.x;
    const int start = wg*5 + ((wg < 256) ? wg : 256);   // 256 WGs x6, 512 x5
    const int cnt   = 5 + (wg < 256 ? 1 : 0);
    int b = start >> 6, tile = start & 63;

    f32x4 hacc[2] = {{0.f,0.f,0.f,0.f},{0.f,0.f,0.f,0.f}};
    float zacc = 0.f;

#pragma unroll 1
    for (int i = 0; i < cnt; i++) {
        // re-pin every iteration: forces the live ranges to stay in the AGPR file
        PIN_A(ah1[0]); PIN_A(ah1[1]);
#pragma unroll
        for (int nt = 0; nt < 2; nt++)
#pragma unroll
            for (int ks = 0; ks < 4; ks++) { PIN_A(ah2[nt][ks]); PIN_A(wb3[nt][ks]); }
        PIN_A(hacc[0]); PIN_A(hacc[1]);

        const int gt  = tile*64 + t;
        const int len = lengths[b];
        const bool last = (i == cnt - 1);
        const int bn = b + (tile == 63), tilen = (tile + 1) & 63;

        // ---- global loads (issued before B1: barrier wait hides latency) ----
        const ushort* xb = Xbf + ((size_t)b*GTOK + tile*64)*32;
        s16x8 xf[4];
#pragma unroll
        for (int tt = 0; tt < 4; tt++)
            xf[tt] = *(const s16x8*)(xb + (tt*16 + l15)*32 + q*8);
        float sl = slog[((size_t)b*GTOK + gt)*4 + wav];

        __syncthreads();                               // B1 (orders prev head-agg
                                                       //  reads vs Hhi/wexpT writes)
        // wexp (softmax shift cancels; z from SAME bf16 weights -> ratio exact)
        {
            float wxf = (gt <= len) ? __expf(sl) : 0.f;
            ushort w16 = (ushort)(pkbf(wxf, wxf) & 0xffffu);
            wexpT[wav][t] = w16;
            zacc += bf2f(w16);
        }

        // ====== layer 1: A=w1 (AGPR), B=X (regs from global) -> Hhi (swizzled) ==
#pragma unroll
        for (int tt = 0; tt < 4; tt++) {
            const int m = tt*16 + l15;
            s16x8 bh = xf[tt];
#pragma unroll
            for (int nt = 0; nt < 2; nt++) {
                f32x4 acc = {0.f, 0.f, 0.f, 0.f};
                acc = __builtin_amdgcn_mfma_f32_16x16x32_bf16(ah1[nt], bh, acc, 0, 0, 0);
                uint2 uh = {pkbf(fmaxf(acc[0]+bv1[nt][0],0.f), fmaxf(acc[1]+bv1[nt][1],0.f)),
                            pkbf(fmaxf(acc[2]+bv1[nt][2],0.f), fmaxf(acc[3]+bv1[nt][3],0.f))};
                *(uint2*)&Hhi[m][hswz(m, nb0 + nt*16 + q*4)] = uh;
            }
        }
        __syncthreads();                               // B2

        // ====== layer 2: A=w2 (AGPR), B=Hhi -> H2 ======
#pragma unroll
        for (int tt = 0; tt < 4; tt++) {
            const int m = tt*16 + l15;
            s16x8 bh[4];
#pragma unroll
            for (int ks = 0; ks < 4; ks++)
                bh[ks] = *(const s16x8*)&Hhi[m][hswz(m, ks*32 + q*8)];
#pragma unroll
            for (int nt = 0; nt < 2; nt++) {
                f32x4 acc = {0.f, 0.f, 0.f, 0.f};
#pragma unroll
                for (int ks = 0; ks < 4; ks++)
                    acc = __builtin_amdgcn_mfma_f32_16x16x32_bf16(ah2[nt][ks], bh[ks], acc, 0, 0, 0);
                uint2 uh = {pkbf(fmaxf(acc[0]+bv2[nt][0],0.f), fmaxf(acc[1]+bv2[nt][1],0.f)),
                            pkbf(fmaxf(acc[2]+bv2[nt][2],0.f), fmaxf(acc[3]+bv2[nt][3],0.f))};
                *(uint2*)&H2[m][hswz(m, nb0 + nt*16 + q*4)] = uh;
            }
        }
        __syncthreads();                               // B3

        // ====== layer 3: A=tokens (H2), B=w3 (AGPR) -> encT (feature-major) ====
#pragma unroll
        for (int tt = 0; tt < 4; tt++) {
            const int m = tt*16 + l15;
            s16x8 a3[4];
#pragma unroll
            for (int ks = 0; ks < 4; ks++)
                a3[ks] = *(const s16x8*)&H2[m][hswz(m, ks*32 + q*8)];
#pragma unroll
            for (int nt = 0; nt < 2; nt++) {
                f32x4 acc = {0.f,0.f,0.f,0.f};
#pragma unroll
                for (int ks = 0; ks < 4; ks++)
                    acc = __builtin_amdgcn_mfma_f32_16x16x32_bf16(a3[ks], wb3[nt][ks], acc, 0, 0, 0);
                uint2 uh = {pkbf(fmaxf(acc[0]+b3l[nt],0.f), fmaxf(acc[1]+b3l[nt],0.f)),
                            pkbf(fmaxf(acc[2]+b3l[nt],0.f), fmaxf(acc[3]+b3l[nt],0.f))};
                *(uint2*)&encT[nb0 + nt*16 + l15][tt*16 + q*4] = uh;
            }
        }

        // ====== head aggregation: MFMA with persistent AGPR C accumulator ====
        {
            s16x8 af0 = *(const s16x8*)&wexpT[l15][q*8];
            s16x8 af1 = *(const s16x8*)&wexpT[l15][32 + q*8];
#pragma unroll
            for (int nt = 0; nt < 2; nt++) {
                const ushort* erow = &encT[nb0 + nt*16 + l15][0];
                hacc[nt] = __builtin_amdgcn_mfma_f32_16x16x32_bf16(
                               af0, *(const s16x8*)(erow + q*8), hacc[nt], 0, 0, 0);
                hacc[nt] = __builtin_amdgcn_mfma_f32_16x16x32_bf16(
                               af1, *(const s16x8*)(erow + 32 + q*8), hacc[nt], 0, 0, 0);
            }
        }

        // ---- flush P/z accumulators at batch boundary or range end ----
        if (tile == 63 || last) {
            float* outp = partials + (size_t)b * PREC;
            if (q == 0) {
#pragma unroll
                for (int nt = 0; nt < 2; nt++)
#pragma unroll
                    for (int r = 0; r < 4; r++)
                        atomicAdd(&outp[r*128 + nb0 + nt*16 + l15], hacc[nt][r]);
            }
            float z = zacc;
#pragma unroll
            for (int mask = 1; mask <= 32; mask <<= 1) z += __shfl_xor(z, mask);
            if (lane == 0) atomicAdd(&outp[512 + wav], z);
            hacc[0] = f32x4{0.f,0.f,0.f,0.f};
            hacc[1] = f32x4{0.f,0.f,0.f,0.f};
            zacc = 0.f;
        }
        b = bn; tile = tilen;
    }
}

// ---------------- final: feat -> rho MLP -> sigmoid (512 thr, split-k) ---------
__global__ __launch_bounds__(512) void final_kernel(
    const float* __restrict__ partials,
    const float* __restrict__ rw1, const float* __restrict__ rb1,
    const float* __restrict__ rw2, const float* __restrict__ rb2,
    const float* __restrict__ rw3, const float* __restrict__ rb3,
    float* __restrict__ out)
{
    const int b = blockIdx.x, tid = threadIdx.x;
    const int n = tid & 127, h = tid >> 7;         // neuron, k-slice
    __shared__ float feat[512];
    __shared__ float p[4][128];
    __shared__ float r1s[128];
    __shared__ float r2s[128];
    __shared__ float zsh[4];
    const float* pb = partials + (size_t)b * PREC;
    if (tid < 4) zsh[tid] = pb[512 + tid];
    __syncthreads();
    feat[tid] = pb[tid] / zsh[tid >> 7];
    __syncthreads();

    // layer 1: 512 -> 128, split-k 4-way (coalesced rw1[k*128+n])
    {
        float a = 0.f;
        const float* w = rw1 + h*128*128 + n;
        const float* f = feat + h*128;
#pragma unroll 16
        for (int k = 0; k < 128; k++) a += f[k] * w[k*128];
        p[h][n] = a;
    }
    __syncthreads();
    if (h == 0) r1s[n] = fmaxf(p[0][n] + p[1][n] + p[2][n] + p[3][n] + rb1[n], 0.f);
    __syncthreads();

    // layer 2: 128 -> 128, split-k 4-way
    {
        float a = 0.f;
        const float* w = rw2 + h*32*128 + n;
        const float* f = r1s + h*32;
#pragma unroll 16
        for (int k = 0; k < 32; k++) a += f[k] * w[k*128];
        p[h][n] = a;
    }
    __syncthreads();
    if (h == 0) r2s[n] = fmaxf(p[0][n] + p[1][n] + p[2][n] + p[3][n] + rb2[n], 0.f);
    __syncthreads();

    // layer 3: 128 -> 1, wave 0 shuffle-reduce
    if (tid < 64) {
        float v = r2s[tid] * rw3[tid] + r2s[tid + 64] * rw3[tid + 64];
#pragma unroll
        for (int mask = 1; mask <= 32; mask <<= 1) v += __shfl_xor(v, mask);
        if (tid == 0) out[b] = 1.f / (1.f + expf(-(v + rb3[0])));
    }
}

extern "C" void kernel_launch(void* const* d_in, const int* in_sizes, int n_in,
                              void* d_out, int out_size, void* d_ws, size_t ws_size,
                              hipStream_t stream) {
    const float* demo    = (const float*)d_in[0];
    const float* times   = (const float*)d_in[1];
    const float* values  = (const float*)d_in[2];
    const int*   meas    = (const int*)  d_in[3];
    const int*   lengths = (const int*)  d_in[4];
    const float* demo_w1 = (const float*)d_in[5];
    const float* demo_b1 = (const float*)d_in[6];
    const float* demo_w2 = (const float*)d_in[7];
    const float* demo_b2 = (const float*)d_in[8];
    const float* phi_w1  = (const float*)d_in[9];
    const float* phi_b1  = (const float*)d_in[10];
    const float* phi_w2  = (const float*)d_in[11];
    const float* phi_b2  = (const float*)d_in[12];
    const float* phi_w3  = (const float*)d_in[13];
    const float* phi_b3  = (const float*)d_in[14];
    // d_in[15..22]: psi network + rho_attn — dead code (softmax shift-invariance)
    const float* W_k     = (const float*)d_in[23];
    const float* W_q     = (const float*)d_in[24];
    const float* rho_w1  = (const float*)d_in[25];
    const float* rho_b1  = (const float*)d_in[26];
    const float* rho_w2  = (const float*)d_in[27];
    const float* rho_b2  = (const float*)d_in[28];
    const float* rho_w3  = (const float*)d_in[29];
    const float* rho_b3  = (const float*)d_in[30];

    float*  ws       = (float*)d_ws;
    float*  demo_enc = ws;                    // 2048 floats
    float*  w_eff    = ws + 2048;             // 128 floats
    ushort* wT16     = (ushort*)(ws + 2176);  // 36864 ushorts = 18432 floats
    float*  partials = ws + 20608;            // 64*516 = 33024 floats -> ends 53632
    ushort* Xbf      = (ushort*)(ws + 53632); // 64*4160*32 ushorts = 4,259,840 floats
    float*  slog     = ws + 53632 + 4259840;  // 64*4160*4 floats

    prep_all<<<449, 128, 0, stream>>>(demo, demo_w1, demo_b1, demo_w2, demo_b2,
                                      W_k, W_q, phi_w1, phi_w2, phi_w3,
                                      demo_enc, w_eff, wT16, partials);
    featurize<<<dim3(65, NB), 256, 0, stream>>>(times, values, meas,
                                                demo_enc, w_eff, Xbf, slog);
    fused_main<<<NWG, 256, 0, stream>>>(
        lengths, Xbf, slog, wT16, phi_b1, phi_b2, phi_b3, partials);
    final_kernel<<<NB, 512, 0, stream>>>(partials, rho_w1, rho_b1, rho_w2, rho_b2,
                                         rho_w3, rho_b3, (float*)d_out);
}

// Round 12
// 159.373 us; speedup vs baseline: 1.0988x; 1.0988x over previous
//
#include <hip/hip_runtime.h>
#include <hip/hip_bf16.h>
#include <math.h>

#define TT     4096        // T
#define NWG    768         // persistent workgroups (3/CU)
#define PREC   516         // per-batch accumulator: 4*128 P + 4 z
#define NB     64          // batch

typedef short s16x8 __attribute__((ext_vector_type(8)));
typedef float f32x4 __attribute__((ext_vector_type(4)));

// 100^(-i/7), i=0..7  (inverse timescales)
__device__ __constant__ float INV_TS[8] = {
    1.0f,                 0.5179474679231213f, 0.2682695795279726f, 0.1389495494373138f,
    0.0719685673001152f,  0.0372759372031494f, 0.0193069772888325f, 0.01f };

__device__ __forceinline__ ushort f2bf(float f) {        // RNE (prep only)
    uint u = __float_as_uint(f);
    return (ushort)((u + 0x7fffu + ((u >> 16) & 1u)) >> 16);
}
__device__ __forceinline__ float bf2f(ushort h) {
    return __uint_as_float(((uint)h) << 16);
}
// packed f32x2 -> bf16x2 (RNE), single HW instr on gfx950
__device__ __forceinline__ uint pkbf(float a, float b) {
    union { __hip_bfloat162 h; uint u; } cv;
    cv.h = __float22bfloat162_rn(make_float2(a, b));
    return cv.u;
}
// 16B-granule swizzle: phys_granule = (g - 2*row) & 15
// NOTE (r8 post-mortem): conflict-neutral per bank math AND per counter, but the
// r7 register allocation (no spill, AGPR-resident weights) was verified WITH it.
// Do not remove: r8 removed it and spill returned (WRITE 2.1->5.2MB, +4.3us).
__device__ __forceinline__ int hswz(int m, int col) {
    return ((((col >> 3) - 2 * (m & 7)) & 15) << 3) | (col & 7);
}
// pin a fragment into the AGPR file (MFMA sources A/B from AGPR on gfx950)
#define PIN_A(v) asm volatile("" : "+a"(v))

// ---------------- prep: demo enc + zero partials | w_eff | weight prep ----------
__global__ __launch_bounds__(128) void prep_all(
    const float* __restrict__ demo,
    const float* __restrict__ dw1, const float* __restrict__ db1,
    const float* __restrict__ dw2, const float* __restrict__ db2,
    const float* __restrict__ W_k, const float* __restrict__ W_q,
    const float* __restrict__ w1, const float* __restrict__ w2,
    const float* __restrict__ w3,
    float* __restrict__ demo_enc, float* __restrict__ w_eff,
    ushort* __restrict__ ws16, float* __restrict__ partials)
{
    const int b = blockIdx.x, tid = threadIdx.x;
    if (b < NB) {
        for (int j = tid; j < PREC; j += 128) partials[b*PREC + j] = 0.f;
        __shared__ float h[128];
        float a = db1[tid];
#pragma unroll
        for (int k = 0; k < 8; k++) a += demo[b*8 + k] * dw1[k*128 + tid];
        h[tid] = fmaxf(a, 0.f);
        __syncthreads();
        if (tid < 32) {
            float e = db2[tid];
#pragma unroll 8
            for (int k = 0; k < 128; k++) e += h[k] * dw2[k*32 + tid];
            demo_enc[b*32 + tid] = e;
        }
    } else if (b == NB) {
        // w_eff[f][h] = (W_k[f, h*64:(h+1)*64] . W_q[h]) / 8
        const int f = tid >> 2, hh = tid & 3;
        float s = 0.f;
#pragma unroll 8
        for (int d = 0; d < 64; d++) s += W_k[f*256 + hh*64 + d] * W_q[hh*64 + d];
        w_eff[f*4 + hh] = s * 0.125f;
    } else {
        ushort* w1T = ws16;             // [128][32]
        ushort* w2T = ws16 + 4096;      // [128][128]
        ushort* w3T = ws16 + 20480;     // [128][128]
        const int n = (b - 65) & 127, which = (b - 65) >> 7, k = tid;
        if (which == 0)      w2T[n*128 + k] = f2bf(w2[k*128 + n]);
        else if (which == 1) w3T[n*128 + k] = f2bf(w3[k*128 + n]);
        else if (k < 32)     w1T[n*32  + k] = f2bf(w1[k*128 + n]);
    }
}

// ---------------- persistent fused main ----------------------------------------
__global__ void __launch_bounds__(256)
__attribute__((amdgpu_waves_per_eu(3, 3)))
fused_main(
    const float* __restrict__ times,  const float* __restrict__ values,
    const int*   __restrict__ meas,   const int*   __restrict__ lengths,
    const float* __restrict__ demo_enc, const float* __restrict__ w_eff,
    const ushort* __restrict__ wT16,
    const float* __restrict__ b1, const float* __restrict__ b2,
    const float* __restrict__ b3,
    float* __restrict__ partials)
{
    const ushort* w1T = wT16;
    const ushort* w2T = wT16 + 4096;
    const ushort* w3T = wT16 + 20480;

    // ---- LDS arena with lifetime-based aliasing (50.75 KB -> 3 WG/CU) ----
    __shared__ __align__(16) char arena[51968];
    ushort (*Hhi )[136]    = (ushort(*)[136])(arena);            // 17408 B
    ushort (*encT)[88]     = (ushort(*)[88]) (arena);            // 22528 B (alias)
    ushort (*H2  )[136]    = (ushort(*)[136])(arena + 22528);    // 17408 B
    ushort (*Xhi )[40]     = (ushort(*)[40]) (arena + 39936);    //  5120 B
    float  (*spart)[4][64] = (float(*)[4][64])(arena + 45056);   //  4096 B
    ushort (*wexpT)[88]    = (ushort(*)[88]) (arena + 49152);    //  2816 B

    const int tid  = threadIdx.x;
    const int lane = tid & 63, wav = tid >> 6;
    const int l15  = lane & 15, q = lane >> 4;
    const int nb0  = wav * 32;
    const int t    = lane;                  // token slot; wav = feature-group

    // zero wexpT rows 4..15 once (A-operand padding rows)
    for (int i = tid; i < 12*88/2; i += 256) ((uint*)&wexpT[4][0])[i] = 0u;

    // ---- load weight fragments ONCE; they live in AGPRs across the whole loop --
    s16x8 ah1[2];    f32x4 bv1[2];
    s16x8 ah2[2][4]; f32x4 bv2[2];
    s16x8 wb3[2][4]; float b3l[2];
#pragma unroll
    for (int nt = 0; nt < 2; nt++) {
        const int np = nb0 + nt*16 + l15;
        ah1[nt] = *(const s16x8*)(w1T + np*32 + q*8);
        bv1[nt] = *(const f32x4*)(b1 + nb0 + nt*16 + q*4);
#pragma unroll
        for (int ks = 0; ks < 4; ks++) {
            ah2[nt][ks] = *(const s16x8*)(w2T + np*128 + ks*32 + q*8);
            wb3[nt][ks] = *(const s16x8*)(w3T + np*128 + ks*32 + q*8);
        }
        bv2[nt] = *(const f32x4*)(b2 + nb0 + nt*16 + q*4);
        b3l[nt] = b3[np];
    }

    // ---- contiguous chunk range for this WG (b-locality -> register P-accum) ----
    const int wg = blockIdx.x;
    const int start = wg*5 + ((wg < 256) ? wg : 256);   // 256 WGs x6, 512 x5
    const int cnt   = 5 + (wg < 256 ? 1 : 0);
    int b = start >> 6, tile = start & 63;

    f32x4 hacc[2] = {{0.f,0.f,0.f,0.f},{0.f,0.f,0.f,0.f}};
    float zacc = 0.f;

    // prefetch first chunk's inputs
    float pf_tm = 0.f, pf_vl = 0.f; int pf_mm = -1;
    {
        const int gt = tile*64 + t;
        if (gt >= 1) {
            const int ti = b*TT + gt - 1;
            pf_tm = times[ti]; pf_vl = values[ti]; pf_mm = meas[ti];
        }
    }

#pragma unroll 1
    for (int i = 0; i < cnt; i++) {
        // re-pin every iteration: forces the live ranges to stay in the AGPR file
        PIN_A(ah1[0]); PIN_A(ah1[1]);
#pragma unroll
        for (int nt = 0; nt < 2; nt++)
#pragma unroll
            for (int ks = 0; ks < 4; ks++) { PIN_A(ah2[nt][ks]); PIN_A(wb3[nt][ks]); }
        PIN_A(hacc[0]); PIN_A(hacc[1]);

        const int gt  = tile*64 + t;
        const int len = lengths[b];
        const bool last = (i == cnt - 1);
        const int bn = b + (tile == 63), tilen = (tile + 1) & 63;

        // ---- feature build (wave-specialized) ----
        float x[8];
        if (gt == 0) {
#pragma unroll
            for (int j = 0; j < 8; j++) x[j] = demo_enc[b*32 + wav*8 + j];
        } else {
            if (wav == 0) {
#pragma unroll
                for (int j = 0; j < 8; j++) x[j] = __sinf(pf_tm * INV_TS[j]);
            } else if (wav == 1) {
#pragma unroll
                for (int j = 0; j < 8; j++) x[j] = __cosf(pf_tm * INV_TS[j]);
            } else if (wav == 2) {
                x[0] = pf_vl;
#pragma unroll
                for (int j = 1; j < 8; j++) x[j] = (pf_mm == j-1) ? 1.f : 0.f;
            } else {
#pragma unroll
                for (int j = 0; j < 8; j++) x[j] = (pf_mm == 7+j) ? 1.f : 0.f;
            }
        }
        // attention-logit partials
        {
            float s0 = 0, s1 = 0, s2 = 0, s3 = 0;
#pragma unroll
            for (int j = 0; j < 8; j++) {
                const float* we = w_eff + (wav*8 + j)*4;
                s0 += x[j]*we[0]; s1 += x[j]*we[1]; s2 += x[j]*we[2]; s3 += x[j]*we[3];
            }
            spart[wav][0][t] = s0; spart[wav][1][t] = s1;
            spart[wav][2][t] = s2; spart[wav][3][t] = s3;
        }
        // X -> bf16
        {
            uint4 uh = {pkbf(x[0],x[1]), pkbf(x[2],x[3]), pkbf(x[4],x[5]), pkbf(x[6],x[7])};
            *(uint4*)&Xhi[t][wav*8] = uh;
        }
        // prefetch next chunk's inputs (hidden under compute)
        if (!last) {
            const int gt2 = tilen*64 + t;
            if (gt2 >= 1) {
                const int ti = bn*TT + gt2 - 1;
                pf_tm = times[ti]; pf_vl = values[ti]; pf_mm = meas[ti];
            } else { pf_mm = -1; }
        }
        __syncthreads();                               // B1
        // wexp (softmax shift cancels; z from SAME bf16 weights -> ratio exact)
        {
            float ss = spart[0][wav][t] + spart[1][wav][t]
                     + spart[2][wav][t] + spart[3][wav][t];
            float wxf = (gt <= len) ? __expf(ss) : 0.f;
            ushort w16 = (ushort)(pkbf(wxf, wxf) & 0xffffu);
            wexpT[wav][t] = w16;
            zacc += bf2f(w16);
        }

        // ====== layer 1: A=w1 (AGPR), B=X -> Hhi (swizzled) ======
#pragma unroll
        for (int tt = 0; tt < 4; tt++) {
            const int m = tt*16 + l15;
            s16x8 bh = *(const s16x8*)&Xhi[m][q*8];
#pragma unroll
            for (int nt = 0; nt < 2; nt++) {
                f32x4 acc = {0.f, 0.f, 0.f, 0.f};
                acc = __builtin_amdgcn_mfma_f32_16x16x32_bf16(ah1[nt], bh, acc, 0, 0, 0);
                uint2 uh = {pkbf(fmaxf(acc[0]+bv1[nt][0],0.f), fmaxf(acc[1]+bv1[nt][1],0.f)),
                            pkbf(fmaxf(acc[2]+bv1[nt][2],0.f), fmaxf(acc[3]+bv1[nt][3],0.f))};
                *(uint2*)&Hhi[m][hswz(m, nb0 + nt*16 + q*4)] = uh;
            }
        }
        __syncthreads();                               // B2

        // ====== layer 2: A=w2 (AGPR), B=Hhi -> H2 ======
#pragma unroll
        for (int tt = 0; tt < 4; tt++) {
            const int m = tt*16 + l15;
            s16x8 bh[4];
#pragma unroll
            for (int ks = 0; ks < 4; ks++)
                bh[ks] = *(const s16x8*)&Hhi[m][hswz(m, ks*32 + q*8)];
#pragma unroll
            for (int nt = 0; nt < 2; nt++) {
                f32x4 acc = {0.f, 0.f, 0.f, 0.f};
#pragma unroll
                for (int ks = 0; ks < 4; ks++)
                    acc = __builtin_amdgcn_mfma_f32_16x16x32_bf16(ah2[nt][ks], bh[ks], acc, 0, 0, 0);
                uint2 uh = {pkbf(fmaxf(acc[0]+bv2[nt][0],0.f), fmaxf(acc[1]+bv2[nt][1],0.f)),
                            pkbf(fmaxf(acc[2]+bv2[nt][2],0.f), fmaxf(acc[3]+bv2[nt][3],0.f))};
                *(uint2*)&H2[m][hswz(m, nb0 + nt*16 + q*4)] = uh;
            }
        }
        __syncthreads();                               // B3

        // ====== layer 3: A=tokens (H2), B=w3 (AGPR) -> encT (feature-major) ====
#pragma unroll
        for (int tt = 0; tt < 4; tt++) {
            const int m = tt*16 + l15;
            s16x8 a3[4];
#pragma unroll
            for (int ks = 0; ks < 4; ks++)
                a3[ks] = *(const s16x8*)&H2[m][hswz(m, ks*32 + q*8)];
#pragma unroll
            for (int nt = 0; nt < 2; nt++) {
                f32x4 acc = {0.f,0.f,0.f,0.f};
#pragma unroll
                for (int ks = 0; ks < 4; ks++)
                    acc = __builtin_amdgcn_mfma_f32_16x16x32_bf16(a3[ks], wb3[nt][ks], acc, 0, 0, 0);
                uint2 uh = {pkbf(fmaxf(acc[0]+b3l[nt],0.f), fmaxf(acc[1]+b3l[nt],0.f)),
                            pkbf(fmaxf(acc[2]+b3l[nt],0.f), fmaxf(acc[3]+b3l[nt],0.f))};
                *(uint2*)&encT[nb0 + nt*16 + l15][tt*16 + q*4] = uh;
            }
        }

        // ====== head aggregation: MFMA with persistent AGPR C accumulator ====
        {
            s16x8 af0 = *(const s16x8*)&wexpT[l15][q*8];
            s16x8 af1 = *(const s16x8*)&wexpT[l15][32 + q*8];
#pragma unroll
            for (int nt = 0; nt < 2; nt++) {
                const ushort* erow = &encT[nb0 + nt*16 + l15][0];
                hacc[nt] = __builtin_amdgcn_mfma_f32_16x16x32_bf16(
                               af0, *(const s16x8*)(erow + q*8), hacc[nt], 0, 0, 0);
                hacc[nt] = __builtin_amdgcn_mfma_f32_16x16x32_bf16(
                               af1, *(const s16x8*)(erow + 32 + q*8), hacc[nt], 0, 0, 0);
            }
        }

        // ---- flush P/z accumulators at batch boundary or range end ----
        if (tile == 63 || last) {
            float* outp = partials + (size_t)b * PREC;
            if (q == 0) {
#pragma unroll
                for (int nt = 0; nt < 2; nt++)
#pragma unroll
                    for (int r = 0; r < 4; r++)
                        atomicAdd(&outp[r*128 + nb0 + nt*16 + l15], hacc[nt][r]);
            }
            float z = zacc;
#pragma unroll
            for (int mask = 1; mask <= 32; mask <<= 1) z += __shfl_xor(z, mask);
            if (lane == 0) atomicAdd(&outp[512 + wav], z);
            hacc[0] = f32x4{0.f,0.f,0.f,0.f};
            hacc[1] = f32x4{0.f,0.f,0.f,0.f};
            zacc = 0.f;
        }
        b = bn; tile = tilen;
    }
}

// ---------------- final: feat -> rho MLP -> sigmoid (512 thr, split-k) ---------
__global__ __launch_bounds__(512) void final_kernel(
    const float* __restrict__ partials,
    const float* __restrict__ rw1, const float* __restrict__ rb1,
    const float* __restrict__ rw2, const float* __restrict__ rb2,
    const float* __restrict__ rw3, const float* __restrict__ rb3,
    float* __restrict__ out)
{
    const int b = blockIdx.x, tid = threadIdx.x;
    const int n = tid & 127, h = tid >> 7;         // neuron, k-slice
    __shared__ float feat[512];
    __shared__ float p[4][128];
    __shared__ float r1s[128];
    __shared__ float r2s[128];
    __shared__ float zsh[4];
    const float* pb = partials + (size_t)b * PREC;
    if (tid < 4) zsh[tid] = pb[512 + tid];
    __syncthreads();
    feat[tid] = pb[tid] / zsh[tid >> 7];
    __syncthreads();

    // layer 1: 512 -> 128, split-k 4-way (coalesced rw1[k*128+n])
    {
        float a = 0.f;
        const float* w = rw1 + h*128*128 + n;
        const float* f = feat + h*128;
#pragma unroll 16
        for (int k = 0; k < 128; k++) a += f[k] * w[k*128];
        p[h][n] = a;
    }
    __syncthreads();
    if (h == 0) r1s[n] = fmaxf(p[0][n] + p[1][n] + p[2][n] + p[3][n] + rb1[n], 0.f);
    __syncthreads();

    // layer 2: 128 -> 128, split-k 4-way
    {
        float a = 0.f;
        const float* w = rw2 + h*32*128 + n;
        const float* f = r1s + h*32;
#pragma unroll 16
        for (int k = 0; k < 32; k++) a += f[k] * w[k*128];
        p[h][n] = a;
    }
    __syncthreads();
    if (h == 0) r2s[n] = fmaxf(p[0][n] + p[1][n] + p[2][n] + p[3][n] + rb2[n], 0.f);
    __syncthreads();

    // layer 3: 128 -> 1, wave 0 shuffle-reduce
    if (tid < 64) {
        float v = r2s[tid] * rw3[tid] + r2s[tid + 64] * rw3[tid + 64];
#pragma unroll
        for (int mask = 1; mask <= 32; mask <<= 1) v += __shfl_xor(v, mask);
        if (tid == 0) out[b] = 1.f / (1.f + expf(-(v + rb3[0])));
    }
}

extern "C" void kernel_launch(void* const* d_in, const int* in_sizes, int n_in,
                              void* d_out, int out_size, void* d_ws, size_t ws_size,
                              hipStream_t stream) {
    const float* demo    = (const float*)d_in[0];
    const float* times   = (const float*)d_in[1];
    const float* values  = (const float*)d_in[2];
    const int*   meas    = (const int*)  d_in[3];
    const int*   lengths = (const int*)  d_in[4];
    const float* demo_w1 = (const float*)d_in[5];
    const float* demo_b1 = (const float*)d_in[6];
    const float* demo_w2 = (const float*)d_in[7];
    const float* demo_b2 = (const float*)d_in[8];
    const float* phi_w1  = (const float*)d_in[9];
    const float* phi_b1  = (const float*)d_in[10];
    const float* phi_w2  = (const float*)d_in[11];
    const float* phi_b2  = (const float*)d_in[12];
    const float* phi_w3  = (const float*)d_in[13];
    const float* phi_b3  = (const float*)d_in[14];
    // d_in[15..22]: psi network + rho_attn — dead code (softmax shift-invariance)
    const float* W_k     = (const float*)d_in[23];
    const float* W_q     = (const float*)d_in[24];
    const float* rho_w1  = (const float*)d_in[25];
    const float* rho_b1  = (const float*)d_in[26];
    const float* rho_w2  = (const float*)d_in[27];
    const float* rho_b2  = (const float*)d_in[28];
    const float* rho_w3  = (const float*)d_in[29];
    const float* rho_b3  = (const float*)d_in[30];

    float*  ws       = (float*)d_ws;
    float*  demo_enc = ws;                    // 2048 floats
    float*  w_eff    = ws + 2048;             // 128 floats
    ushort* wT16     = (ushort*)(ws + 2176);  // 36864 ushorts = 18432 floats
    float*  partials = ws + 20608;            // 64*516 floats

    prep_all<<<449, 128, 0, stream>>>(demo, demo_w1, demo_b1, demo_w2, demo_b2,
                                      W_k, W_q, phi_w1, phi_w2, phi_w3,
                                      demo_enc, w_eff, wT16, partials);
    fused_main<<<NWG, 256, 0, stream>>>(
        times, values, meas, lengths, demo_enc, w_eff, wT16,
        phi_b1, phi_b2, phi_b3, partials);
    final_kernel<<<NB, 512, 0, stream>>>(partials, rho_w1, rho_b1, rho_w2, rho_b2,
                                         rho_w3, rho_b3, (float*)d_out);
}